// Round 1
// baseline (132.344 us; speedup 1.0000x reference)
//
#include <hip/hip_runtime.h>

// ColorDenseCRFLoss: exact Gaussian color bilateral loss.
// out = -1e-7/4 * sum_{n,p,q} exp(-0.5*||f_p-f_q||^2) * (seg_p . seg_q)

#define N_BATCH 4
#define IH 128
#define IW 128
#define OH 64
#define OW 64
#define P 4096   // OH*OW
#define KC 21
#define KPAD 24  // pad 21 -> 24 floats (6 x float4), pads are zero
#define PT 4     // p's per thread in pair kernel
#define QCHUNK 128

static constexpr float INV_SIGMA = 1.0f / 15.0f;
static constexpr float OUT_SCALE = -1e-7f / 4.0f;

// One thread per downsampled pixel: compute color feature (and 0.5*||f||^2)
// plus 2x2 avg-pooled segmentation vector.
__global__ void crf_prep_kernel(const float* __restrict__ img,
                                const float* __restrict__ seg,
                                float4* __restrict__ feats,   // [N*P]
                                float* __restrict__ segs)     // [N*P*KPAD]
{
    int t = blockIdx.x * blockDim.x + threadIdx.x;
    if (t >= N_BATCH * P) return;
    int n = t >> 12;       // / 4096
    int p = t & (P - 1);
    int y = p >> 6;
    int x = p & 63;
    int iy = 2 * y, ix = 2 * x;

    const float* ib = img + ((size_t)n * 3 * IH * IW) + (size_t)iy * IW + ix;
    float f0 = ib[0] * INV_SIGMA;
    float f1 = ib[(size_t)IH * IW] * INV_SIGMA;
    float f2 = ib[2 * (size_t)IH * IW] * INV_SIGMA;
    float h = 0.5f * (f0 * f0 + f1 * f1 + f2 * f2);
    feats[t] = make_float4(f0, f1, f2, h);

    const float* sb = seg + ((size_t)n * KC * IH * IW) + (size_t)iy * IW + ix;
    float* so = segs + (size_t)t * KPAD;
#pragma unroll
    for (int k = 0; k < KC; ++k) {
        const float* s = sb + (size_t)k * IH * IW;
        so[k] = 0.25f * ((s[0] + s[1]) + (s[IW] + s[IW + 1]));
    }
    so[21] = 0.0f; so[22] = 0.0f; so[23] = 0.0f;
}

// Each thread owns PT consecutive p's (seg vectors held in registers) and
// streams a QCHUNK range of q. q loads are wave-uniform (broadcast).
__global__ void crf_pair_kernel(const float4* __restrict__ feats,
                                const float4* __restrict__ segs4,  // [N*P*6]
                                float* __restrict__ out)
{
    int n = blockIdx.z;
    int pbase = blockIdx.y * (blockDim.x * PT) + threadIdx.x * PT;
    int q0 = blockIdx.x * QCHUNK;

    const float4* fN = feats + (size_t)n * P;
    const float4* sN = segs4 + (size_t)n * P * 6;

    float4 fp[PT];
    float4 sp[PT][6];
    float acc[PT];
#pragma unroll
    for (int i = 0; i < PT; ++i) {
        fp[i] = fN[pbase + i];
#pragma unroll
        for (int j = 0; j < 6; ++j) sp[i][j] = sN[(size_t)(pbase + i) * 6 + j];
        acc[i] = 0.0f;
    }

    for (int q = q0; q < q0 + QCHUNK; ++q) {
        float4 fq = fN[q];
        float4 sq[6];
#pragma unroll
        for (int j = 0; j < 6; ++j) sq[j] = sN[(size_t)q * 6 + j];
#pragma unroll
        for (int i = 0; i < PT; ++i) {
            float d = fp[i].x * fq.x + fp[i].y * fq.y + fp[i].z * fq.z;
            float arg = d - fp[i].w - fq.w;      // = -0.5*||f_p - f_q||^2
            arg = fminf(arg, 0.0f);              // matches max(d2, 0) in ref
            float e = __expf(arg);
            float s = 0.0f;
#pragma unroll
            for (int j = 0; j < 6; ++j) {
                s += sp[i][j].x * sq[j].x + sp[i][j].y * sq[j].y +
                     sp[i][j].z * sq[j].z + sp[i][j].w * sq[j].w;
            }
            acc[i] += e * s;
        }
    }

    float part = (acc[0] + acc[1]) + (acc[2] + acc[3]);
#pragma unroll
    for (int off = 32; off > 0; off >>= 1)
        part += __shfl_down(part, off, 64);

    __shared__ float wsum[4];
    int lane = threadIdx.x & 63;
    int wid = threadIdx.x >> 6;
    if (lane == 0) wsum[wid] = part;
    __syncthreads();
    if (threadIdx.x == 0) {
        float tot = (wsum[0] + wsum[1]) + (wsum[2] + wsum[3]);
        atomicAdd(out, tot * OUT_SCALE);
    }
}

extern "C" void kernel_launch(void* const* d_in, const int* in_sizes, int n_in,
                              void* d_out, int out_size, void* d_ws, size_t ws_size,
                              hipStream_t stream)
{
    const float* images = (const float*)d_in[0];   // [4,3,128,128]
    const float* segm   = (const float*)d_in[1];   // [4,21,128,128]
    float* out = (float*)d_out;                    // [1]

    float4* feats = (float4*)d_ws;                                   // 256 KB
    float*  segs  = (float*)((char*)d_ws + (size_t)N_BATCH * P * sizeof(float4)); // 1.5 MB

    hipMemsetAsync(d_out, 0, sizeof(float), stream);

    crf_prep_kernel<<<dim3((N_BATCH * P + 255) / 256), dim3(256), 0, stream>>>(
        images, segm, feats, segs);

    // grid: 32 q-chunks x 4 p-blocks x 4 batches = 512 blocks
    crf_pair_kernel<<<dim3(P / QCHUNK, P / (256 * PT), N_BATCH), dim3(256), 0, stream>>>(
        feats, (const float4*)segs, out);
}

// Round 2
// 92.040 us; speedup vs baseline: 1.4379x; 1.4379x over previous
//
#include <hip/hip_runtime.h>

// ColorDenseCRFLoss via MFMA:
// out = -1e-7/4 * sum_{n,p,q} exp(-0.5*||f_p-f_q||^2) * (seg_p . seg_q)
// Both inner products computed by mfma_f32_16x16x32_bf16 on augmented
// per-pixel bf16 vectors (hi/lo split => ~fp32 product precision).

#define N_BATCH 4
#define IH 128
#define IW 128
#define P 4096   // 64x64 downsampled pixels per batch
#define KC 21

using short8  = __attribute__((ext_vector_type(8))) short;
using floatx4 = __attribute__((ext_vector_type(4))) float;

static constexpr float INV_SIGMA = 1.0f / 15.0f;
static constexpr float LOG2E     = 1.4426950408889634f;
static constexpr float OUT_SCALE = -1e-7f / 4.0f;

// ws layout (bytes):
//   [0,64)      zero page (16B used, read by padded quads)
//   argA: N*P rows x 16 bf16 (32B each)
//   argB: N*P rows x 16 bf16 (32B each)
//   seg : N*P rows x 24 bf16 (48B each)
#define ZP_OFF   0
#define ARGA_OFF 64
#define ARGB_OFF (ARGA_OFF + N_BATCH * P * 32)
#define SEG_OFF  (ARGB_OFF + N_BATCH * P * 32)

__device__ __forceinline__ ushort f2bf(float x) {  // RNE float->bf16 bits
    unsigned u = __builtin_bit_cast(unsigned, x);
    unsigned r = (u + 0x7FFFu + ((u >> 16) & 1u)) >> 16;
    return (ushort)r;
}
__device__ __forceinline__ float bf2f(ushort h) {
    return __builtin_bit_cast(float, (unsigned)h << 16);
}

__global__ void crf_prep(const float* __restrict__ img,
                         const float* __restrict__ seg,
                         char* __restrict__ wsb,
                         float* __restrict__ out)
{
    int t = blockIdx.x * blockDim.x + threadIdx.x;
    if (t == 0) out[0] = 0.0f;
    if (t < 16) ((float*)(wsb + ZP_OFF))[t] = 0.0f;  // zero page
    if (t >= N_BATCH * P) return;

    int n = t >> 12;
    int p = t & (P - 1);
    int y = p >> 6, x = p & 63;

    const float* ib = img + (size_t)n * 3 * IH * IW + (size_t)(2 * y) * IW + 2 * x;
    float f0 = ib[0] * INV_SIGMA;
    float f1 = ib[IH * IW] * INV_SIGMA;
    float f2 = ib[2 * IH * IW] * INV_SIGMA;
    float h = 0.5f * (f0 * f0 + f1 * f1 + f2 * f2);

    // A-side color, pre-scaled by log2(e); hi/lo bf16 split
    float fa0 = f0 * LOG2E, fa1 = f1 * LOG2E, fa2 = f2 * LOG2E;
    ushort ah0 = f2bf(fa0), ah1 = f2bf(fa1), ah2 = f2bf(fa2);
    ushort al0 = f2bf(fa0 - bf2f(ah0));
    ushort al1 = f2bf(fa1 - bf2f(ah1));
    ushort al2 = f2bf(fa2 - bf2f(ah2));
    float nhL = -h * LOG2E;
    ushort nhh = f2bf(nhL), nhl = f2bf(nhL - bf2f(nhh));
    // B-side color, unscaled; hi/lo split
    ushort bh0 = f2bf(f0), bh1 = f2bf(f1), bh2 = f2bf(f2);
    ushort bl0 = f2bf(f0 - bf2f(bh0));
    ushort bl1 = f2bf(f1 - bf2f(bh1));
    ushort bl2 = f2bf(f2 - bf2f(bh2));
    float hL = h * LOG2E;
    ushort hbh = f2bf(hL), hbl = f2bf(hL - bf2f(hbh));

    const ushort ONE = 0x3F80, NEG1 = 0xBF80;
    // dot(argA_p, argB_q) = log2e * (f_p.f_q - h_p - h_q)
    ushort rA[16] = {ah0, ah1, ah2, ah0, ah1, ah2, al0, al1, al2, al0, al1, al2,
                     nhh, nhl, NEG1, NEG1};
    ushort rB[16] = {bh0, bh1, bh2, bl0, bl1, bl2, bh0, bh1, bh2, bl0, bl1, bl2,
                     ONE, ONE, hbh, hbl};

    short8 vA0, vA1, vB0, vB1;
#pragma unroll
    for (int j = 0; j < 8; ++j) {
        vA0[j] = (short)rA[j];     vA1[j] = (short)rA[8 + j];
        vB0[j] = (short)rB[j];     vB1[j] = (short)rB[8 + j];
    }
    short8* dA = (short8*)(wsb + ARGA_OFF + (size_t)t * 32);
    dA[0] = vA0; dA[1] = vA1;
    short8* dB = (short8*)(wsb + ARGB_OFF + (size_t)t * 32);
    dB[0] = vB0; dB[1] = vB1;

    // 2x2 average-pooled softmax vector (bilinear 0.5x == avg pool), 24 bf16
    const float* sb = seg + (size_t)n * KC * IH * IW + (size_t)(2 * y) * IW + 2 * x;
    ushort rS[24];
#pragma unroll
    for (int k = 0; k < KC; ++k) {
        const float* s = sb + (size_t)k * IH * IW;
        rS[k] = f2bf(0.25f * ((s[0] + s[1]) + (s[IW] + s[IW + 1])));
    }
    rS[21] = 0; rS[22] = 0; rS[23] = 0;
    short8 vS0, vS1, vS2;
#pragma unroll
    for (int j = 0; j < 8; ++j) {
        vS0[j] = (short)rS[j]; vS1[j] = (short)rS[8 + j]; vS2[j] = (short)rS[16 + j];
    }
    short8* dS = (short8*)(wsb + SEG_OFF + (size_t)t * 48);
    dS[0] = vS0; dS[1] = vS1; dS[2] = vS2;
}

// Each wave: 4 p-tiles (64 rows, A frags in regs) x 8 q-tiles (streamed,
// 1-deep prefetch). Per q-tile: 8 MFMAs + 16 x (min,exp2,fma).
__global__ __launch_bounds__(256) void crf_pair(const char* __restrict__ wsb,
                                                float* __restrict__ out)
{
    int n = blockIdx.z;
    int wave = threadIdx.x >> 6;
    int lane = threadIdx.x & 63;
    int quad = lane >> 4;
    int l16  = lane & 15;

    const char* argA = wsb + ARGA_OFF + (size_t)n * P * 32;
    const char* argB = wsb + ARGB_OFF + (size_t)n * P * 32;
    const char* segT = wsb + SEG_OFF  + (size_t)n * P * 48;
    const char* zp   = wsb + ZP_OFF;

    // A fragments: 4 p-tiles, rows prow..prow+63
    int prow = blockIdx.y * 64;
    short8 aArg[4], aSeg[4];
#pragma unroll
    for (int i = 0; i < 4; ++i) {
        int m = prow + i * 16 + l16;
        aArg[i] = *(const short8*)(quad < 2 ? argA + m * 32 + quad * 16 : zp);
        aSeg[i] = *(const short8*)(quad < 3 ? segT + m * 48 + quad * 16 : zp);
    }

    float part = 0.0f;
    int qt0 = blockIdx.x * 32 + wave;          // q-tiles qt0 + 4t, t=0..7
    int q = qt0 * 16 + l16;
    short8 bArg = *(const short8*)(quad < 2 ? argB + q * 32 + quad * 16 : zp);
    short8 bSeg = *(const short8*)(quad < 3 ? segT + q * 48 + quad * 16 : zp);

    for (int t = 0; t < 8; ++t) {
        int qn = (t < 7) ? (qt0 + 4 * (t + 1)) * 16 + l16 : q;
        short8 bArgN = *(const short8*)(quad < 2 ? argB + qn * 32 + quad * 16 : zp);
        short8 bSegN = *(const short8*)(quad < 3 ? segT + qn * 48 + quad * 16 : zp);

        floatx4 zero = {0.0f, 0.0f, 0.0f, 0.0f};
#pragma unroll
        for (int i = 0; i < 4; ++i) {
            floatx4 g  = __builtin_amdgcn_mfma_f32_16x16x32_bf16(aSeg[i], bSeg, zero, 0, 0, 0);
            floatx4 ar = __builtin_amdgcn_mfma_f32_16x16x32_bf16(aArg[i], bArg, zero, 0, 0, 0);
#pragma unroll
            for (int j = 0; j < 4; ++j) {
                float e = __builtin_amdgcn_exp2f(fminf(ar[j], 0.0f));
                part += e * g[j];
            }
        }
        bArg = bArgN; bSeg = bSegN;
    }

    // reduce: wave -> block -> global
#pragma unroll
    for (int off = 32; off > 0; off >>= 1)
        part += __shfl_down(part, off, 64);
    __shared__ float wsum[4];
    if (lane == 0) wsum[wave] = part;
    __syncthreads();
    if (threadIdx.x == 0)
        atomicAdd(out, ((wsum[0] + wsum[1]) + (wsum[2] + wsum[3])) * OUT_SCALE);
}

extern "C" void kernel_launch(void* const* d_in, const int* in_sizes, int n_in,
                              void* d_out, int out_size, void* d_ws, size_t ws_size,
                              hipStream_t stream)
{
    const float* images = (const float*)d_in[0];   // [4,3,128,128]
    const float* segm   = (const float*)d_in[1];   // [4,21,128,128]
    float* out = (float*)d_out;                    // [1]
    char* wsb = (char*)d_ws;                       // ~1.79 MB used

    crf_prep<<<dim3((N_BATCH * P + 255) / 256), dim3(256), 0, stream>>>(
        images, segm, wsb, out);
    crf_pair<<<dim3(8, 64, N_BATCH), dim3(256), 0, stream>>>(wsb, out);
}